// Round 6
// baseline (486.407 us; speedup 1.0000x reference)
//
#include <hip/hip_runtime.h>
#include <hip/hip_fp16.h>

#define T_DIM 7
#define H_DIM 96
#define W_DIM 96
#define HW    (H_DIM*W_DIM)          // 9216
#define L_DIM (T_DIM*HW)             // 64512
#define NTAPS 27

typedef __attribute__((ext_vector_type(8))) _Float16 f16x8;
typedef __attribute__((ext_vector_type(4))) float f32x4;

// barrier that does NOT drain vmcnt (keeps global prefetches in flight)
__device__ __forceinline__ void lds_barrier() {
    asm volatile("s_waitcnt lgkmcnt(0)" ::: "memory");
    __builtin_amdgcn_s_barrier();
    __builtin_amdgcn_sched_barrier(0);
}

// ---------------------------------------------------------------------------
// prep_weights: [O][C][27] fp32 -> [27][O(64-pad)][C] f16, slot rotated by o
// (2-way LDS reads, free). Image is what the kernel stages linearly.
// ---------------------------------------------------------------------------
__global__ void prep_weights(const float* __restrict__ woff0,
                             const float* __restrict__ w0,
                             const float* __restrict__ woff1,
                             const float* __restrict__ w1,
                             unsigned short* __restrict__ dst)
{
    int idx = blockIdx.x * 256 + threadIdx.x;
    const int per = NTAPS * 64 * 64;           // 110592
    if (idx >= 4 * per) return;
    int which = idx / per;
    int r     = idx % per;
    int tap   = r / 4096;
    int o     = (r >> 6) & 63;
    int c     = r & 63;
    const float* src = (which == 0) ? woff0 : (which == 1) ? w0
                     : (which == 2) ? woff1 : w1;
    int omax = (which == 0 || which == 2) ? 54 : 64;
    float v = 0.f;
    if (o < omax) v = src[(o * 64 + c) * NTAPS + tap];
    __half h = __float2half(v);
    int slot = (((c >> 3) + o) & 7);
    int pos  = tap * 4096 + o * 64 + slot * 8 + (c & 7);
    dst[which * per + pos] = __half_as_ushort(h);
}

// ---------------------------------------------------------------------------
// transpose_x: x [C=64][L] fp32 -> xt [L][64] f16 (packed dwords)
// ---------------------------------------------------------------------------
__global__ void transpose_x(const float* __restrict__ x, unsigned* __restrict__ xt2)
{
    __shared__ float tile[64][65];
    const int tid = threadIdx.x;
    const int lb  = blockIdx.x * 64;
    const int ln  = tid & 63;
    const int q   = tid >> 6;    // 0..3
#pragma unroll
    for (int i = 0; i < 16; ++i) {
        int c = q + 4 * i;
        tile[ln][c] = x[(size_t)c * L_DIM + lb + ln];
    }
    __syncthreads();
    const int ln2 = tid & 31, q2 = tid >> 5;   // 0..7
#pragma unroll
    for (int i = 0; i < 8; ++i) {
        int ll = q2 + 8 * i;
        __half2 h2 = __float22half2_rn(make_float2(tile[ll][2*ln2], tile[ll][2*ln2+1]));
        xt2[(size_t)(lb + ll) * 32 + ln2] = *reinterpret_cast<unsigned*>(&h2);
    }
}

// ---- per-tap macros (token-pasted register sets => guaranteed static indexing)
#define PARAMS_ISSUE(K, O2, CWH, CW0, G) { \
    int kt_ = (K) / 9; int r9_ = (K) - kt_ * 9; \
    int kh_ = r9_ / 3; int kw_ = r9_ - kh_ * 3; \
    int tp_ = t + kt_ - 1; \
    bool tv_ = (tp_ >= 0) && (tp_ < T_DIM); \
    int tb_ = (tv_ ? tp_ : 0) * HW; \
    if (DEFORM) { \
        float ph_ = (float)(h + kh_ - 1) + (O2).x; \
        float pw_ = (float)(w + kw_ - 1) + (O2).y; \
        float h0f_ = floorf(ph_), w0f_ = floorf(pw_); \
        float lh_ = ph_ - h0f_, lw_ = pw_ - w0f_; \
        int h0_ = (int)h0f_, w0_ = (int)w0f_; \
        _Pragma("unroll") \
        for (int j = 0; j < 4; ++j) { \
            int hj_ = h0_ + (j >> 1), wj_ = w0_ + (j & 1); \
            bool v_ = tv_ && (hj_ >= 0) && (hj_ < H_DIM) && (wj_ >= 0) && (wj_ < W_DIM); \
            float wh_  = (j >> 1) ? lh_ : 1.f - lh_; \
            float wwt_ = (j & 1)  ? lw_ : 1.f - lw_; \
            int hc_ = min(max(hj_, 0), H_DIM - 1); \
            int wc_ = min(max(wj_, 0), W_DIM - 1); \
            CWH[j] = __float2half2_rn(v_ ? wh_ * wwt_ : 0.f); \
            int cb_ = (tb_ + hc_ * W_DIM + wc_) * 128 + lk * 16; \
            G[2*j]   = *(const int4*)(xb + cb_); \
            G[2*j+1] = *(const int4*)(xb + cb_ + 64); \
        } \
    } else { \
        int hj_ = h + kh_ - 1, wj_ = w + kw_ - 1; \
        bool v_ = tv_ && (hj_ >= 0) && (hj_ < H_DIM) && (wj_ >= 0) && (wj_ < W_DIM); \
        int hc_ = min(max(hj_, 0), H_DIM - 1); \
        int wc_ = min(max(wj_, 0), W_DIM - 1); \
        CW0 = v_ ? 1.f : 0.f; \
        int cb_ = (tb_ + hc_ * W_DIM + wc_) * 128 + lk * 16; \
        G[0] = *(const int4*)(xb + cb_); \
        G[1] = *(const int4*)(xb + cb_ + 64); \
    } }

#define CONSUME(G, CWH, CW0, A0, A1) { \
    if (DEFORM) { \
        __half2 va_[8]; \
        const __half2 z2_ = __float2half2_rn(0.f); \
        _Pragma("unroll") \
        for (int p = 0; p < 8; ++p) va_[p] = z2_; \
        _Pragma("unroll") \
        for (int j = 0; j < 4; ++j) { \
            const __half2* g0_ = (const __half2*)&G[2*j]; \
            const __half2* g1_ = (const __half2*)&G[2*j+1]; \
            _Pragma("unroll") \
            for (int d = 0; d < 4; ++d) { \
                va_[d]     = __hfma2(g0_[d], CWH[j], va_[d]); \
                va_[4 + d] = __hfma2(g1_[d], CWH[j], va_[4 + d]); \
            } \
        } \
        A0 = *reinterpret_cast<f16x8*>(&va_[0]); \
        A1 = *reinterpret_cast<f16x8*>(&va_[4]); \
    } else { \
        int4 z0_ = G[0], z1_ = G[1]; \
        if (CW0 == 0.f) { z0_ = make_int4(0,0,0,0); z1_ = make_int4(0,0,0,0); } \
        A0 = *reinterpret_cast<f16x8*>(&z0_); \
        A1 = *reinterpret_cast<f16x8*>(&z1_); \
    } }

#define TAP(K, G, CWH, CW0) { \
    if ((K) + 2 < NTAPS) { \
        const int4* wp_ = (const int4*)(Wt + (size_t)((K) + 2) * 4096); \
        wB0 = wp_[tid]; wB1 = wp_[tid + 256]; \
    } \
    f16x8 a0_, a1_; \
    CONSUME(G, CWH, CW0, a0_, a1_); \
    if ((K) + 2 < NTAPS) { \
        PARAMS_ISSUE((K) + 2, o2n, CWH, CW0, G); \
        if (DEFORM && (K) + 3 < NTAPS) { \
            __half2 oh_ = *(const __half2*)(offp + 2 * ((K) + 3)); \
            o2n = __half22float2(oh_); \
        } \
    } \
    lds_barrier(); \
    if ((K) + 1 < NTAPS) { \
        unsigned char* bw_ = smem + ((((K) + 1) & 1) << 13); \
        *(int4*)(bw_ + tid * 16)        = wA0; \
        *(int4*)(bw_ + 4096 + tid * 16) = wA1; \
        wA0 = wB0; wA1 = wB1; \
    } \
    const unsigned char* br_ = smem + (((K) & 1) << 13) + lr * 128; \
    _Pragma("unroll") \
    for (int n = 0; n < 4; ++n) { \
        f16x8 b0_ = *(const f16x8*)(br_ + n * 2048 + s0); \
        f16x8 b1_ = *(const f16x8*)(br_ + n * 2048 + s1); \
        acc[n] = __builtin_amdgcn_mfma_f32_16x16x32_f16(a0_, b0_, acc[n], 0, 0, 0); \
        acc[n] = __builtin_amdgcn_mfma_f32_16x16x32_f16(a1_, b1_, acc[n], 0, 0, 0); \
    } }

// ---------------------------------------------------------------------------
// dcn_reg: depth-2 register gather pipeline + XCD-contiguous block swizzle.
//   EPI: 0 = +bias -> f16 [loc][64] (offsets); 1 = +bias+leaky -> f16 [loc][64];
//        2 = +bias+residual -> f32 NCDHW d_out
// ---------------------------------------------------------------------------
template<bool DEFORM, int EPI>
__global__ __launch_bounds__(256, DEFORM ? 3 : 4)
void dcn_reg(const unsigned short* __restrict__ xin,   // f16 [L][64]
             const unsigned short* __restrict__ off,   // f16 [L][64] (DEFORM)
             const unsigned short* __restrict__ Wt,    // f16 [27][64][64] swizzled
             const float* __restrict__ bias, int nbias,
             const float* __restrict__ resid,          // f32 NCDHW (EPI==2)
             float* __restrict__ outf,
             unsigned short* __restrict__ outh)
{
    __shared__ __align__(16) unsigned char smem[16384];   // 2 x 8KB weight bufs

    const int tid  = threadIdx.x;
    const int wave = tid >> 6, lane = tid & 63;
    const int lr   = lane & 15, lk = lane >> 4;

    // XCD-contiguous swizzle: grid=1008, 8 XCDs, 126 blocks each (bijective)
    const int bid = blockIdx.x;
    const int wg  = (bid & 7) * 126 + (bid >> 3);

    const int nt    = HW / 64;                 // 144
    const int tile  = wg % nt;
    const int t     = wg / nt;
    const int wloc0 = tile * 64 + wave * 16;
    const int lbase = t * HW + wloc0;

    const int mypos = wloc0 + lr;
    const int h = mypos / W_DIM;
    const int w = mypos - h * W_DIM;

    f32x4 acc[4];
#pragma unroll
    for (int n = 0; n < 4; ++n) acc[n] = (f32x4){0.f, 0.f, 0.f, 0.f};

    const unsigned char* xb = (const unsigned char*)xin;
    const unsigned short* offp = DEFORM ? (off + (size_t)(lbase + lr) * 64) : nullptr;

    // swizzled slot offsets for B reads (2-way, free)
    const int s0 = ((lk + lr) & 7) << 4;
    const int s1 = ((lk + 4 + lr) & 7) << 4;

    int4    gA[8], gB[8];
    int4    wA0, wA1, wB0, wB1;
    __half2 cwhA[4], cwhB[4];
    float   cw0A = 0.f, cw0B = 0.f;
    float2  o2n = make_float2(0.f, 0.f);

    // ---- prologue: weights taps 0,1; gathers taps 0,1; stage tap0 -> buf0
    {
        const int4* wp0 = (const int4*)(Wt);
        wA0 = wp0[tid]; wA1 = wp0[tid + 256];
        const int4* wp1 = (const int4*)(Wt + 4096);
        wB0 = wp1[tid]; wB1 = wp1[tid + 256];
    }
    if (DEFORM) {
        __half2 oh0 = *(const __half2*)(offp);
        float2 o2a = __half22float2(oh0);
        PARAMS_ISSUE(0, o2a, cwhA, cw0A, gA);
        __half2 oh1 = *(const __half2*)(offp + 2);
        float2 o2b = __half22float2(oh1);
        PARAMS_ISSUE(1, o2b, cwhB, cw0B, gB);
        __half2 oh2 = *(const __half2*)(offp + 4);
        o2n = __half22float2(oh2);
    } else {
        float2 zz = make_float2(0.f, 0.f);
        PARAMS_ISSUE(0, zz, cwhA, cw0A, gA);
        PARAMS_ISSUE(1, zz, cwhB, cw0B, gB);
    }
    *(int4*)(smem + tid * 16)        = wA0;
    *(int4*)(smem + 4096 + tid * 16) = wA1;
    wA0 = wB0; wA1 = wB1;

#pragma unroll 1
    for (int kk = 0; kk < NTAPS; kk += 2) {
        TAP(kk, gA, cwhA, cw0A);
        if (kk + 1 < NTAPS) {
            TAP(kk + 1, gB, cwhB, cw0B);
        }
    }

    // ---- epilogue. C/D: col = lr (out ch within n*16), row = lk*4+i (loc)
    float bv[4];
#pragma unroll
    for (int n = 0; n < 4; ++n) {
        int o = n * 16 + lr;
        bv[n] = (o < nbias) ? bias[o] : 0.f;
    }
    if (EPI == 0 || EPI == 1) {
#pragma unroll
        for (int n = 0; n < 4; ++n)
#pragma unroll
            for (int i = 0; i < 4; ++i) {
                int row = lk * 4 + i;
                float vv = acc[n][i] + bv[n];
                if (EPI == 1) vv = (vv > 0.f) ? vv : 0.1f * vv;
                outh[(size_t)(lbase + row) * 64 + n * 16 + lr] = __half_as_ushort(__float2half(vv));
            }
    } else {
        __syncthreads();   // weight bufs dead; reuse smem per-wave for transpose
        float* tf = (float*)(smem + wave * 4096);
#pragma unroll
        for (int n = 0; n < 4; ++n)
#pragma unroll
            for (int i = 0; i < 4; ++i) {
                int row = lk * 4 + i;
                int och = n * 16 + lr;
                tf[row * 64 + ((och + 2 * row) & 63)] = acc[n][i] + bv[n];
            }
        int j = lane & 15, gq = lane >> 4;
#pragma unroll
        for (int it = 0; it < 16; ++it) {
            int och = gq * 16 + it;
            float val = tf[j * 64 + ((och + 2 * j) & 63)];
            size_t gi = (size_t)och * L_DIM + lbase + j;
            outf[gi] = val + resid[gi];
        }
    }
}

// ---------------------------------------------------------------------------
extern "C" void kernel_launch(void* const* d_in, const int* in_sizes, int n_in,
                              void* d_out, int out_size, void* d_ws, size_t ws_size,
                              hipStream_t stream)
{
    const float* x     = (const float*)d_in[0];
    const float* woff0 = (const float*)d_in[1];
    const float* boff0 = (const float*)d_in[2];
    const float* w0    = (const float*)d_in[3];
    const float* b0    = (const float*)d_in[4];
    const float* woff1 = (const float*)d_in[5];
    const float* boff1 = (const float*)d_in[6];
    const float* w1    = (const float*)d_in[7];
    const float* b1    = (const float*)d_in[8];
    float* out = (float*)d_out;

    unsigned char* ws = (unsigned char*)d_ws;
    unsigned short* Wt  = (unsigned short*)ws;                  // 884736 B (4x f16 [27][64][64] swz)
    unsigned short* xt  = (unsigned short*)(ws + 884736);       // 8257536 B f16 [L][64]
    unsigned short* y   = (unsigned short*)(ws + 9142272);      // 8257536 B f16 [L][64]
    unsigned short* offb= (unsigned short*)(ws + 17399808);     // 8257536 B f16 [L][64]

    prep_weights<<<1728, 256, 0, stream>>>(woff0, w0, woff1, w1, Wt);
    transpose_x<<<1008, 256, 0, stream>>>(x, (unsigned*)xt);

    const int grid = T_DIM * (HW / 64);   // 1008
    const int WSZ  = NTAPS * 64 * 64;     // 110592

    // layer 0
    dcn_reg<false, 0><<<grid, 256, 0, stream>>>(xt, nullptr, Wt,           boff0, 54, nullptr, nullptr, offb);
    dcn_reg<true,  1><<<grid, 256, 0, stream>>>(xt, offb,    Wt + WSZ,     b0,    64, nullptr, nullptr, y);
    // layer 1
    dcn_reg<false, 0><<<grid, 256, 0, stream>>>(y,  nullptr, Wt + 2 * WSZ, boff1, 54, nullptr, nullptr, offb);
    dcn_reg<true,  2><<<grid, 256, 0, stream>>>(y,  offb,    Wt + 3 * WSZ, b1,    64, x, out, nullptr);
}

// Round 7
// 307.010 us; speedup vs baseline: 1.5843x; 1.5843x over previous
//
#include <hip/hip_runtime.h>
#include <hip/hip_fp16.h>

#define T_DIM 7
#define H_DIM 96
#define W_DIM 96
#define HW    (H_DIM*W_DIM)          // 9216
#define L_DIM (T_DIM*HW)             // 64512
#define NTAPS 27

typedef __attribute__((ext_vector_type(8))) _Float16 f16x8;
typedef __attribute__((ext_vector_type(4))) float f32x4;

// barrier that does NOT drain vmcnt (keeps global prefetches in flight)
__device__ __forceinline__ void lds_barrier() {
    asm volatile("s_waitcnt lgkmcnt(0)" ::: "memory");
    __builtin_amdgcn_s_barrier();
    __builtin_amdgcn_sched_barrier(0);
}

// async global->LDS, 16B per lane. LDS dest must be wave-uniform base + lane*16.
#define GLOAD16(gp, lp) \
    __builtin_amdgcn_global_load_lds((const __attribute__((address_space(1))) unsigned int*)(gp), \
                                     (__attribute__((address_space(3))) unsigned int*)(lp), 16, 0, 0)

// ---------------------------------------------------------------------------
// prep_weights: [O][C][27] fp32 -> [27][O(64-pad)][C] f16, slot rotated by o
// (2-way LDS reads = free). Kernel stages this image LINEARLY via gload_lds.
// ---------------------------------------------------------------------------
__global__ void prep_weights(const float* __restrict__ woff0,
                             const float* __restrict__ w0,
                             const float* __restrict__ woff1,
                             const float* __restrict__ w1,
                             unsigned short* __restrict__ dst)
{
    int idx = blockIdx.x * 256 + threadIdx.x;
    const int per = NTAPS * 64 * 64;           // 110592
    if (idx >= 4 * per) return;
    int which = idx / per;
    int r     = idx % per;
    int tap   = r / 4096;
    int o     = (r >> 6) & 63;
    int c     = r & 63;
    const float* src = (which == 0) ? woff0 : (which == 1) ? w0
                     : (which == 2) ? woff1 : w1;
    int omax = (which == 0 || which == 2) ? 54 : 64;
    float v = 0.f;
    if (o < omax) v = src[(o * 64 + c) * NTAPS + tap];
    __half h = __float2half(v);
    int slot = (((c >> 3) + o) & 7);
    int pos  = tap * 4096 + o * 64 + slot * 8 + (c & 7);
    dst[which * per + pos] = __half_as_ushort(h);
}

// ---------------------------------------------------------------------------
// transpose_x: x [C=64][L] fp32 -> xt [L][64] f16 (packed dwords)
// ---------------------------------------------------------------------------
__global__ void transpose_x(const float* __restrict__ x, unsigned* __restrict__ xt2)
{
    __shared__ float tile[64][65];
    const int tid = threadIdx.x;
    const int lb  = blockIdx.x * 64;
    const int ln  = tid & 63;
    const int q   = tid >> 6;    // 0..3
#pragma unroll
    for (int i = 0; i < 16; ++i) {
        int c = q + 4 * i;
        tile[ln][c] = x[(size_t)c * L_DIM + lb + ln];
    }
    __syncthreads();
    const int ln2 = tid & 31, q2 = tid >> 5;   // 0..7
#pragma unroll
    for (int i = 0; i < 8; ++i) {
        int ll = q2 + 8 * i;
        __half2 h2 = __float22half2_rn(make_float2(tile[ll][2*ln2], tile[ll][2*ln2+1]));
        xt2[(size_t)(lb + ll) * 32 + ln2] = *reinterpret_cast<unsigned*>(&h2);
    }
}

// ---- per-tap helpers (single register set; depth-1 pipeline) ---------------
#define PARAMS_ISSUE(K, O2) { \
    int kt_ = (K) / 9; int r9_ = (K) - kt_ * 9; \
    int kh_ = r9_ / 3; int kw_ = r9_ - kh_ * 3; \
    int tp_ = t + kt_ - 1; \
    bool tv_ = (tp_ >= 0) && (tp_ < T_DIM); \
    int tb_ = (tv_ ? tp_ : 0) * HW; \
    if (DEFORM) { \
        float ph_ = (float)(h + kh_ - 1) + (O2).x; \
        float pw_ = (float)(w + kw_ - 1) + (O2).y; \
        float h0f_ = floorf(ph_), w0f_ = floorf(pw_); \
        float lh_ = ph_ - h0f_, lw_ = pw_ - w0f_; \
        int h0_ = (int)h0f_, w0_ = (int)w0f_; \
        _Pragma("unroll") \
        for (int j = 0; j < 4; ++j) { \
            int hj_ = h0_ + (j >> 1), wj_ = w0_ + (j & 1); \
            bool v_ = tv_ && (hj_ >= 0) && (hj_ < H_DIM) && (wj_ >= 0) && (wj_ < W_DIM); \
            float wh_  = (j >> 1) ? lh_ : 1.f - lh_; \
            float wwt_ = (j & 1)  ? lw_ : 1.f - lw_; \
            int hc_ = min(max(hj_, 0), H_DIM - 1); \
            int wc_ = min(max(wj_, 0), W_DIM - 1); \
            cwh[j] = __float2half2_rn(v_ ? wh_ * wwt_ : 0.f); \
            int cb_ = (tb_ + hc_ * W_DIM + wc_) * 128 + lk * 16; \
            g[2*j]   = *(const int4*)(xb + cb_); \
            g[2*j+1] = *(const int4*)(xb + cb_ + 64); \
        } \
    } else { \
        int hj_ = h + kh_ - 1, wj_ = w + kw_ - 1; \
        bool v_ = tv_ && (hj_ >= 0) && (hj_ < H_DIM) && (wj_ >= 0) && (wj_ < W_DIM); \
        int hc_ = min(max(hj_, 0), H_DIM - 1); \
        int wc_ = min(max(wj_, 0), W_DIM - 1); \
        cw0 = v_ ? 1.f : 0.f; \
        int cb_ = (tb_ + hc_ * W_DIM + wc_) * 128 + lk * 16; \
        g[0] = *(const int4*)(xb + cb_); \
        g[1] = *(const int4*)(xb + cb_ + 64); \
    } }

#define CONSUME(A0, A1) { \
    if (DEFORM) { \
        __half2 va_[8]; \
        const __half2 z2_ = __float2half2_rn(0.f); \
        _Pragma("unroll") \
        for (int p = 0; p < 8; ++p) va_[p] = z2_; \
        _Pragma("unroll") \
        for (int j = 0; j < 4; ++j) { \
            const __half2* g0_ = (const __half2*)&g[2*j]; \
            const __half2* g1_ = (const __half2*)&g[2*j+1]; \
            _Pragma("unroll") \
            for (int d = 0; d < 4; ++d) { \
                va_[d]     = __hfma2(g0_[d], cwh[j], va_[d]); \
                va_[4 + d] = __hfma2(g1_[d], cwh[j], va_[4 + d]); \
            } \
        } \
        A0 = *reinterpret_cast<f16x8*>(&va_[0]); \
        A1 = *reinterpret_cast<f16x8*>(&va_[4]); \
    } else { \
        int4 z0_ = g[0], z1_ = g[1]; \
        if (cw0 == 0.f) { z0_ = make_int4(0,0,0,0); z1_ = make_int4(0,0,0,0); } \
        A0 = *reinterpret_cast<f16x8*>(&z0_); \
        A1 = *reinterpret_cast<f16x8*>(&z1_); \
    } }

// ---------------------------------------------------------------------------
// dcn_reg: depth-1 register gather pipeline; weights staged via gload_lds into
// a 2x8KB LDS double-buffer; counted-vmcnt schedule (no vmcnt(0) in loop);
// XCD-contiguous block swizzle for L2 locality of gathers.
//   EPI: 0 = +bias -> f16 [loc][64]; 1 = +bias+leaky -> f16 [loc][64];
//        2 = +bias+residual -> f32 NCDHW d_out
// ---------------------------------------------------------------------------
template<bool DEFORM, int EPI>
__global__ __launch_bounds__(256, 4)
void dcn_reg(const unsigned short* __restrict__ xin,   // f16 [L][64]
             const unsigned short* __restrict__ off,   // f16 [L][64] (DEFORM)
             const unsigned short* __restrict__ Wt,    // f16 [27][64][64] swizzled
             const float* __restrict__ bias, int nbias,
             const float* __restrict__ resid,          // f32 NCDHW (EPI==2)
             float* __restrict__ outf,
             unsigned short* __restrict__ outh)
{
    __shared__ __align__(16) unsigned char smem[16384];   // 2 x 8KB weight bufs

    const int tid  = threadIdx.x;
    const int wave = tid >> 6, lane = tid & 63;
    const int lr   = lane & 15, lk = lane >> 4;

    // XCD-contiguous swizzle: grid=1008 = 8 XCDs x 126 blocks (bijective)
    const int bid = blockIdx.x;
    const int wg  = (bid & 7) * 126 + (bid >> 3);

    const int nt    = HW / 64;                 // 144
    const int tile  = wg % nt;
    const int t     = wg / nt;
    const int wloc0 = tile * 64 + wave * 16;
    const int lbase = t * HW + wloc0;

    const int mypos = wloc0 + lr;
    const int h = mypos / W_DIM;
    const int w = mypos - h * W_DIM;

    f32x4 acc[4];
#pragma unroll
    for (int n = 0; n < 4; ++n) acc[n] = (f32x4){0.f, 0.f, 0.f, 0.f};

    const unsigned char* xb = (const unsigned char*)xin;
    const unsigned short* offp = DEFORM ? (off + (size_t)(lbase + lr) * 64) : nullptr;
    const unsigned char* wbase = (const unsigned char*)Wt;

    // swizzled slot offsets for B reads (2-way, free)
    const int s0 = ((lk + lr) & 7) << 4;
    const int s1 = ((lk + 4 + lr) & 7) << 4;

    int4    g[8];
    __half2 cwh[4];
    float   cw0 = 0.f;
    float2  o2n = make_float2(0.f, 0.f);

    // ---- prologue: offsets(0); weights(0)->buf0; gathers(0); offsets(1)
    float2 o2a = make_float2(0.f, 0.f);
    if (DEFORM) o2a = __half22float2(*(const __half2*)(offp));
    {
        const unsigned char* wsrc = wbase + tid * 16;
        unsigned char* ld0 = smem + wave * 1024;
        GLOAD16(wsrc,        ld0);
        GLOAD16(wsrc + 4096, ld0 + 4096);
    }
    PARAMS_ISSUE(0, o2a);
    if (DEFORM) o2n = __half22float2(*(const __half2*)(offp + 2));

#pragma unroll 1
    for (int k = 0; k < NTAPS; ++k) {
        // 1. my weights(k) have landed (gathers stay in flight: counted wait)
        if (DEFORM) asm volatile("s_waitcnt vmcnt(8)" ::: "memory");
        else        asm volatile("s_waitcnt vmcnt(2)" ::: "memory");
        // 2. all waves' weights(k) landed; previous readers of buf[(k+1)&1] done
        lds_barrier();
        // 3. issue async weight stage for tap k+1 into the other buffer
        if (k + 1 < NTAPS) {
            const unsigned char* wsrc = wbase + (size_t)(k + 1) * 8192 + tid * 16;
            unsigned char* ld0 = smem + (((k + 1) & 1) << 13) + wave * 1024;
            GLOAD16(wsrc,        ld0);
            GLOAD16(wsrc + 4096, ld0 + 4096);
        }
        // 4. consume gathers(k) -> A-frags (compiler emits counted vmcnt wait)
        f16x8 a0, a1;
        CONSUME(a0, a1);
        // 5. offsets(k+2) first, then params+gathers(k+1) (clean FIFO order)
        if (k + 1 < NTAPS) {
            float2 o2use = o2n;
            if (DEFORM && k + 2 < NTAPS)
                o2n = __half22float2(*(const __half2*)(offp + 2 * (k + 2)));
            PARAMS_ISSUE(k + 1, o2use);
        }
        // 6. B-frag reads (2-way, free) + 8 MFMAs on buf[k&1]
        const unsigned char* br = smem + ((k & 1) << 13) + lr * 128;
#pragma unroll
        for (int n = 0; n < 4; ++n) {
            f16x8 b0 = *(const f16x8*)(br + n * 2048 + s0);
            f16x8 b1 = *(const f16x8*)(br + n * 2048 + s1);
            acc[n] = __builtin_amdgcn_mfma_f32_16x16x32_f16(a0, b0, acc[n], 0, 0, 0);
            acc[n] = __builtin_amdgcn_mfma_f32_16x16x32_f16(a1, b1, acc[n], 0, 0, 0);
        }
    }

    // ---- epilogue. C/D: col = lr (out ch within n*16), row = lk*4+i (loc)
    float bv[4];
#pragma unroll
    for (int n = 0; n < 4; ++n) {
        int o = n * 16 + lr;
        bv[n] = (o < nbias) ? bias[o] : 0.f;
    }
    if (EPI == 0 || EPI == 1) {
#pragma unroll
        for (int n = 0; n < 4; ++n)
#pragma unroll
            for (int i = 0; i < 4; ++i) {
                int row = lk * 4 + i;
                float vv = acc[n][i] + bv[n];
                if (EPI == 1) vv = (vv > 0.f) ? vv : 0.1f * vv;
                outh[(size_t)(lbase + row) * 64 + n * 16 + lr] = __half_as_ushort(__float2half(vv));
            }
    } else {
        __syncthreads();   // weight bufs dead; reuse smem per-wave for transpose
        float* tf = (float*)(smem + wave * 4096);
#pragma unroll
        for (int n = 0; n < 4; ++n)
#pragma unroll
            for (int i = 0; i < 4; ++i) {
                int row = lk * 4 + i;
                int och = n * 16 + lr;
                tf[row * 64 + ((och + 2 * row) & 63)] = acc[n][i] + bv[n];
            }
        __syncthreads();
        int j = lane & 15, gq = lane >> 4;
#pragma unroll
        for (int it = 0; it < 16; ++it) {
            int och = gq * 16 + it;
            float val = tf[j * 64 + ((och + 2 * j) & 63)];
            size_t gi = (size_t)och * L_DIM + lbase + j;
            outf[gi] = val + resid[gi];
        }
    }
}

// ---------------------------------------------------------------------------
extern "C" void kernel_launch(void* const* d_in, const int* in_sizes, int n_in,
                              void* d_out, int out_size, void* d_ws, size_t ws_size,
                              hipStream_t stream)
{
    const float* x     = (const float*)d_in[0];
    const float* woff0 = (const float*)d_in[1];
    const float* boff0 = (const float*)d_in[2];
    const float* w0    = (const float*)d_in[3];
    const float* b0    = (const float*)d_in[4];
    const float* woff1 = (const float*)d_in[5];
    const float* boff1 = (const float*)d_in[6];
    const float* w1    = (const float*)d_in[7];
    const float* b1    = (const float*)d_in[8];
    float* out = (float*)d_out;

    unsigned char* ws = (unsigned char*)d_ws;
    unsigned short* Wt  = (unsigned short*)ws;                  // 884736 B (4x f16 [27][64][64] swz)
    unsigned short* xt  = (unsigned short*)(ws + 884736);       // 8257536 B f16 [L][64]
    unsigned short* y   = (unsigned short*)(ws + 9142272);      // 8257536 B f16 [L][64]
    unsigned short* offb= (unsigned short*)(ws + 17399808);     // 8257536 B f16 [L][64]

    prep_weights<<<1728, 256, 0, stream>>>(woff0, w0, woff1, w1, Wt);
    transpose_x<<<1008, 256, 0, stream>>>(x, (unsigned*)xt);

    const int grid = T_DIM * (HW / 64);   // 1008
    const int WSZ  = NTAPS * 64 * 64;     // 110592

    // layer 0
    dcn_reg<false, 0><<<grid, 256, 0, stream>>>(xt, nullptr, Wt,           boff0, 54, nullptr, nullptr, offb);
    dcn_reg<true,  1><<<grid, 256, 0, stream>>>(xt, offb,    Wt + WSZ,     b0,    64, nullptr, nullptr, y);
    // layer 1
    dcn_reg<false, 0><<<grid, 256, 0, stream>>>(y,  nullptr, Wt + 2 * WSZ, boff1, 54, nullptr, nullptr, offb);
    dcn_reg<true,  2><<<grid, 256, 0, stream>>>(y,  offb,    Wt + 3 * WSZ, b1,    64, x, out, nullptr);
}